// Round 7
// baseline (217.200 us; speedup 1.0000x reference)
//
#include <hip/hip_runtime.h>
#include <hip/hip_bf16.h>

#define BB 4
#define CC 64
#define HH 192
#define WW 192
#define HWSZ (HH*WW)          // 36864
#define HD 96
#define WD 96
#define GG 32
// fused kernel geometry: 512 threads, 128 pixels (4 threads/pixel in phase 1)
#define FTH 512
#define FPX 128
#define FBPB (HWSZ/FPX)       // 288 blocks per batch; grid 1152
// pre kernel geometry: 256 threads, 128 pixels (4px x 8ch per thread)
#define PBLK 128
#define BPB (HWSZ/PBLK)       // 288 blocks per batch; grid 1152

typedef short short8 __attribute__((ext_vector_type(8)));
typedef float f32x4  __attribute__((ext_vector_type(4)));

__device__ __forceinline__ unsigned short f2bf(float f) {
    unsigned u = __float_as_uint(f);
    return (unsigned short)((u + 0x7FFFu + ((u >> 16) & 1u)) >> 16);
}
__device__ __forceinline__ float bf2f(unsigned short s) {
    return __uint_as_float(((unsigned)s) << 16);
}
__device__ __forceinline__ unsigned pk2(float a, float b) {
    return (unsigned)f2bf(a) | ((unsigned)f2bf(b) << 16);
}
__device__ __forceinline__ short8 u4s8(uint4 u) {
    union { uint4 a; short8 b; } cvt; cvt.a = u; return cvt.b;
}

// XCD-slab swizzle for 1152-block grids: presumed xcd = bid%8; give each XCD a
// contiguous 144-block slab so its 4MB L2 holds that slab's x rows.
__device__ __forceinline__ int swz1152(int bid) {
    return (bid & 7) * 144 + (bid >> 3);
}

// ---- single-pass pre-kernel: on-the-fly down+up, df, ||x||, GN sums, min/max ----
// Round-1 configuration: plain __launch_bounds__(256). Do not cap occupancy
// (round-4 (256,4): -20us; round-5 (256,8): 200MB scratch spills).
// XT=1 additionally emits x_t[B][HW][C] (transposed copy) from the already-loaded
// center values via a 4-channel register buffer — feeds k_fused's coalesced path.
// Blocks 0..15 also pack w1/w2 into MFMA B-frag order (cold branch).
template<int XT>
__global__ __launch_bounds__(256) void k_pre(const float* __restrict__ x,
                                             const float* __restrict__ w1,
                                             const float* __restrict__ w2,
                                             unsigned* __restrict__ wf,
                                             float* __restrict__ df,
                                             float* __restrict__ nrm,
                                             float* __restrict__ gnacc,
                                             unsigned* __restrict__ mmmin,
                                             unsigned* __restrict__ mmmax,
                                             float* __restrict__ xt) {
    __shared__ float sgn[64];
    __shared__ float wmn[4], wmx[4];
    int tid = threadIdx.x;
    if (tid < 64) sgn[tid] = 0.f;
    __syncthreads();

    // ---- weight prep (blocks 0..15 only), 2 items/thread, covers 8192 ----
    if (blockIdx.x < 16) {
        #pragma unroll
        for (int rep = 0; rep < 2; ++rep) {
            int i = blockIdx.x*512 + rep*256 + tid;
            if (i < 4096) {
                float2 v = ((const float2*)w1)[i];    // j = i>>5, c0 = (i&31)*2
                int j = i >> 5, cp = i & 31, c0 = cp << 1;
                int fi = ((j >> 4) << 1) + (c0 >> 5);
                int ln = (((c0 & 31) >> 3) << 4) + (j & 15);
                wf[fi*256 + ln*4 + (cp & 3)] = pk2(v.x, v.y);
            } else {
                int i2 = i - 4096;
                float2 v = ((const float2*)w2)[i2];   // c = i2>>6, j0 = (i2&63)*2
                int c = i2 >> 6, jp = i2 & 63, j0 = jp << 1;
                int fi = ((j0 >> 5) << 2) + (c >> 4);
                int ln = (((j0 & 31) >> 3) << 4) + (c & 15);
                wf[4096 + fi*256 + ln*4 + (jp & 3)] = pk2(v.x, v.y);
            }
        }
    }

    int virt = swz1152(blockIdx.x);
    int b = virt / BPB;
    int pb = (virt % BPB) * PBLK;
    int wave = tid >> 6, lane = tid & 63;
    int oct = lane >> 3, grp = lane & 7;
    int p0 = pb + wave*32 + grp*4;
    int h = p0 / WW, w0 = p0 % WW;

    // vertical source mapping (same formula/association as reference)
    float hs = fminf(fmaxf(0.5f*(float)h - 0.25f, 0.f), 95.f);
    int hl = (int)hs; int hh2 = min(hl+1, 95); float fh = hs - (float)hl;
    int r0 = 2*hl, r1 = 2*hh2;

    // horizontal: 4 px share a 4-wide xd column window starting at t0
    int t0 = min(max(w0/2 - 1, 0), 92);
    float wc[4][4];
    #pragma unroll
    for (int i = 0; i < 4; ++i) {
        float wsr = fminf(fmaxf(0.5f*(float)(w0+i) - 0.25f, 0.f), 95.f);
        int wl = (int)wsr; int wh = min(wl+1, 95); float fw = wsr - (float)wl;
        int kl = wl - t0, kh = wh - t0;
        #pragma unroll
        for (int k = 0; k < 4; ++k)
            wc[i][k] = ((k==kl) ? (1.f-fw) : 0.f) + ((k==kh) ? fw : 0.f);
    }

    const float* xb = x + (size_t)b*CC*HWSZ;
    float d[4]  = {0.f,0.f,0.f,0.f};
    float qn[4] = {0.f,0.f,0.f,0.f};
    float gs[4] = {0.f,0.f,0.f,0.f};
    float gq[4] = {0.f,0.f,0.f,0.f};
    #pragma unroll
    for (int half = 0; half < 2; ++half) {
        float4 xbuf[4];
        #pragma unroll
        for (int k4 = 0; k4 < 4; ++k4) {
            int cc = half*4 + k4;
            const float* pc = xb + (size_t)(oct*8 + cc)*HWSZ;
            float4 xc = *(const float4*)(pc + h*WW + w0);
            xbuf[k4] = xc;
            const float* pa = pc + r0*WW + 2*t0;
            const float* pq = pc + r1*WW + 2*t0;
            float T[4];
            #pragma unroll
            for (int k = 0; k < 4; ++k) {
                float2 a0 = *(const float2*)(pa + 2*k);
                float2 a1 = *(const float2*)(pa + WW + 2*k);
                float2 c0 = *(const float2*)(pq + 2*k);
                float2 c1 = *(const float2*)(pq + WW + 2*k);
                // 2x2 average, vertical pairs first (matches reference association)
                float xdA = 0.25f*((a0.x + a1.x) + (a0.y + a1.y));
                float xdB = 0.25f*((c0.x + c1.x) + (c0.y + c1.y));
                T[k] = (1.f-fh)*xdA + fh*xdB;        // h-lerp per column
            }
            float xv[4] = {xc.x, xc.y, xc.z, xc.w};
            float sch = 0.f, qch = 0.f;
            #pragma unroll
            for (int i = 0; i < 4; ++i) {
                // w-lerp via sparse dot: exactly (1-fw)*t0 + fw*t1 (zero terms exact)
                float du = (wc[i][0]*T[0] + wc[i][1]*T[1]) + (wc[i][2]*T[2] + wc[i][3]*T[3]);
                d[i] += fabsf(xv[i] - du);
                float x2 = xv[i]*xv[i];
                qn[i] += x2;
                sch += xv[i];
                qch += x2;
            }
            gs[cc>>1] += sch;
            gq[cc>>1] += qch;
        }
        if (XT) {
            // transpose 4ch x 4px register tile -> x_t[p][c] (16B contiguous stores)
            #pragma unroll
            for (int i = 0; i < 4; ++i) {
                float4 v4 = make_float4(((const float*)&xbuf[0])[i],
                                        ((const float*)&xbuf[1])[i],
                                        ((const float*)&xbuf[2])[i],
                                        ((const float*)&xbuf[3])[i]);
                *(float4*)(xt + ((size_t)b*HWSZ + p0 + i)*CC + oct*8 + half*4) = v4;
            }
        }
    }
    // reduce df / ||x||^2 over the 8 channel-octets (butterfly: all lanes get sum)
    #pragma unroll
    for (int o = 8; o <= 32; o <<= 1) {
        #pragma unroll
        for (int i = 0; i < 4; ++i) {
            d[i]  += __shfl_xor(d[i], o);
            qn[i] += __shfl_xor(qn[i], o);
        }
    }
    if (oct == 0) {
        *(float4*)(df  + (size_t)b*HWSZ + p0) = make_float4(d[0], d[1], d[2], d[3]);
        *(float4*)(nrm + (size_t)b*HWSZ + p0) =
            make_float4(sqrtf(qn[0]), sqrtf(qn[1]), sqrtf(qn[2]), sqrtf(qn[3]));
    }
    // block min/max of df (duplicates across octs are harmless for min/max)
    float mn = fminf(fminf(d[0], d[1]), fminf(d[2], d[3]));
    float mx = fmaxf(fmaxf(d[0], d[1]), fmaxf(d[2], d[3]));
    #pragma unroll
    for (int o = 1; o < 64; o <<= 1) {
        mn = fminf(mn, __shfl_xor(mn, o));
        mx = fmaxf(mx, __shfl_xor(mx, o));
    }
    if (lane == 0) { wmn[wave] = mn; wmx[wave] = mx; }
    // GN group sums: reduce over the 8 px-groups (xor 1,2,4 within octet)
    #pragma unroll
    for (int o = 1; o <= 4; o <<= 1) {
        #pragma unroll
        for (int j = 0; j < 4; ++j) {
            gs[j] += __shfl_xor(gs[j], o);
            gq[j] += __shfl_xor(gq[j], o);
        }
    }
    if (grp == 0) {
        #pragma unroll
        for (int j = 0; j < 4; ++j) {
            atomicAdd(&sgn[2*(oct*4+j)],   gs[j]);
            atomicAdd(&sgn[2*(oct*4+j)+1], gq[j]);
        }
    }
    __syncthreads();
    if (tid < 64) atomicAdd(&gnacc[(size_t)b*64 + tid], sgn[tid]);
    if (tid == 0) {
        float bmn = fminf(fminf(wmn[0], wmn[1]), fminf(wmn[2], wmn[3]));
        float bmx = fmaxf(fmaxf(wmx[0], wmx[1]), fmaxf(wmx[2], wmx[3]));
        atomicMin(&mmmin[b], __float_as_uint(bmn));
        atomicMax(&mmmax[b], __float_as_uint(bmx));
    }
}

// ------- fused: sims + top-k softmax + GN affine (phase 1) + MFMA FFN (phase 2) -------
// XT=1: phase-1 reads x_t[B][HW][C] — 16 channels/thread contiguous (float4,
// 16B/lane) instead of 160 scattered scalar loads. Identical arithmetic order.
// XT=0: round-6 measured path (63.0us). (512,4), LDS 24576 B.
template<int XT>
__global__ __launch_bounds__(FTH, 4) void k_fused(const float* __restrict__ x,
                                                  const float* __restrict__ xt,
                                                  const float* __restrict__ df,
                                                  const float* __restrict__ nrm,
                                                  const unsigned* __restrict__ mmmin,
                                                  const unsigned* __restrict__ mmmax,
                                                  const float* __restrict__ gnacc,
                                                  const float* __restrict__ gw,
                                                  const float* __restrict__ gb,
                                                  const unsigned* __restrict__ wf,
                                                  const float* __restrict__ b1,
                                                  const float* __restrict__ b2,
                                                  float* __restrict__ out) {
    __shared__ __align__(16) unsigned char lds[24576];
    unsigned* se = (unsigned*)lds;                  // 4096 uints
    unsigned* sh = (unsigned*)(lds + 16384);        // 2048 uints
    float* gnv = (float*)(lds + 16384);             // [32 groups][mu, rsigma]

    int tid = threadIdx.x;
    int wv = tid >> 6, lane = tid & 63;
    int q = lane >> 4, m = lane & 15;               // quarter (ch group), pixel row

    int virt = swz1152(blockIdx.x);
    int b = virt / FBPB;
    int pb = (virt % FBPB) * FPX;
    int pxl = wv*16 + m;                            // 0..127 local pixel
    int p = pb + pxl;
    int h = p / WW, w = p % WW;
    int cbase = q*16;

    // finalize GN stats in-block
    if (tid < 32) {
        float n = 2.f*HWSZ;
        float mu  = gnacc[(size_t)b*64 + 2*tid] / n;
        float var = gnacc[(size_t)b*64 + 2*tid + 1] / n - mu*mu;
        gnv[2*tid]   = mu;
        gnv[2*tid+1] = rsqrtf(var + 1e-5f);
    }
    __syncthreads();

    // ================= phase 1 =================
    float dmin = __uint_as_float(mmmin[b]);
    float dmax = __uint_as_float(mmmax[b]);
    float dfp = (df[b*HWSZ+p] - dmin) / (dmax - dmin + 1e-8f);
    dfp = dfp * dfp;
    bool maskv = dfp > 0.3f;
    float conn = 1.f + (maskv ? fmaxf(rintf(dfp * 15.f), 0.f) : 0.f);
    bool process = conn > 1.f;
    int kk = (int)fminf(conn, 9.f);

    const float* xb = x + (size_t)b*CC*HWSZ + p;                 // XT=0 path
    const float* pt = xt + ((size_t)b*HWSZ + p)*CC + cbase;      // XT=1 path
    const int dhv[9] = {-1,-1,-1, 0,0,0, 1,1,1};
    const int dwv[9] = {-1, 0, 1,-1,0,1,-1,0,1};
    bool valid[9]; int offc[9];
    #pragma unroll
    for (int j = 0; j < 9; ++j) {
        int hn = h + dhv[j], wn = w + dwv[j];
        valid[j] = (hn >= 0) && (hn < HH) && (wn >= 0) && (wn < WW);
        offc[j] = valid[j] ? (dhv[j]*WW + dwv[j]) : 0;
    }
    float wtc[9];
    #pragma unroll
    for (int j = 0; j < 9; ++j) wtc[j] = 0.f;

    if (process) {
        float dot[9];
        #pragma unroll
        for (int j = 0; j < 9; ++j) dot[j] = 0.f;
        if (XT) {
            #pragma unroll
            for (int i4 = 0; i4 < 4; ++i4) {         // cc = 4*i4 + r, same order
                float4 X = *(const float4*)(pt + 4*i4);
                float4 N[9];
                #pragma unroll
                for (int j = 0; j < 9; ++j)
                    N[j] = *(const float4*)(pt + (ptrdiff_t)offc[j]*CC + 4*i4);
                #pragma unroll
                for (int r = 0; r < 4; ++r) {
                    float xc = ((const float*)&X)[r];
                    #pragma unroll
                    for (int j = 0; j < 9; ++j)
                        dot[j] += xc * ((const float*)&N[j])[r];
                }
            }
        } else {
            #pragma unroll 4
            for (int cc = 0; cc < 16; ++cc) {
                const float* pc = xb + (size_t)(cbase + cc)*HWSZ;
                float xc = pc[0];
                #pragma unroll
                for (int j = 0; j < 9; ++j)
                    dot[j] += xc * pc[offc[j]];
            }
        }
        #pragma unroll
        for (int j = 0; j < 9; ++j) {
            dot[j] += __shfl_xor(dot[j], 16);       // 4 quarters share px
            dot[j] += __shfl_xor(dot[j], 32);
        }
        float nc = fmaxf(nrm[b*HWSZ+p], 1e-12f);
        float sim[9];
        #pragma unroll
        for (int j = 0; j < 9; ++j) {
            float nj = fmaxf(nrm[b*HWSZ+p+offc[j]], 1e-12f);
            sim[j] = valid[j] ? dot[j] / (nc * nj) : 0.f;
        }
        float S = 0.f;
        float wt[9];
        #pragma unroll
        for (int j = 0; j < 9; ++j) {
            int rank = 0;
            #pragma unroll
            for (int l = 0; l < 9; ++l)
                rank += (sim[l] > sim[j]) || (sim[l] == sim[j] && l < j);
            float ex = (rank < kk) ? expf(sim[j]) : 0.f;  // stable argsort(-sim) top-k
            wt[j] = ex; S += ex;
        }
        float inv = 1.f / fmaxf(S, 1e-12f);
        #pragma unroll
        for (int j = 0; j < 9; ++j)
            wtc[j] = valid[j] ? wt[j] * inv : 0.f;
    }

    float e[16];
    if (XT) {
        #pragma unroll
        for (int i4 = 0; i4 < 4; ++i4) {
            float4 X = *(const float4*)(pt + 4*i4);
            float4 N[9];
            if (process) {
                #pragma unroll
                for (int j = 0; j < 9; ++j)
                    N[j] = *(const float4*)(pt + (ptrdiff_t)offc[j]*CC + 4*i4);
            }
            #pragma unroll
            for (int r = 0; r < 4; ++r) {
                int cc = 4*i4 + r;
                int c = cbase + cc;
                float xc = ((const float*)&X)[r];
                float oc;
                if (process) {
                    float a = 0.f;
                    #pragma unroll
                    for (int j = 0; j < 9; ++j)
                        a += wtc[j] * ((const float*)&N[j])[r];
                    oc = a;
                } else oc = xc;
                int g = c >> 1;
                float mu = gnv[2*g], is = gnv[2*g+1];
                e[cc] = oc + (xc - mu) * is * gw[c] + gb[c];
            }
        }
    } else {
        #pragma unroll 4
        for (int cc = 0; cc < 16; ++cc) {
            int c = cbase + cc;
            const float* pc = xb + (size_t)c*HWSZ;
            float xc = pc[0];
            float oc;
            if (process) {
                float a = 0.f;
                #pragma unroll
                for (int j = 0; j < 9; ++j)
                    a += wtc[j] * pc[offc[j]];
                oc = a;
            } else oc = xc;
            int g = c >> 1;
            float mu = gnv[2*g], is = gnv[2*g+1];
            e[cc] = oc + (xc - mu) * is * gw[c] + gb[c];
        }
    }

    // e -> A-frag order: tile wv, kc=q>>1, k = 16*(q&1)+j
    {
        int kc = q >> 1, qo = q & 1;
        unsigned* dst = se + (wv*2 + kc)*256;
        int la = 32*qo + m;
        uint4 ua, ub;
        ua.x = pk2(e[0],e[1]);  ua.y = pk2(e[2],e[3]);
        ua.z = pk2(e[4],e[5]);  ua.w = pk2(e[6],e[7]);
        ub.x = pk2(e[8],e[9]);  ub.y = pk2(e[10],e[11]);
        ub.z = pk2(e[12],e[13]); ub.w = pk2(e[14],e[15]);
        *(uint4*)(dst + la*4)      = ua;
        *(uint4*)(dst + (la+16)*4) = ub;
    }
    __syncthreads();

    // ================= phase 2: MFMA FFN (tile = wv, 16 px) =================
    const unsigned* wf1g = wf;
    const unsigned* wf2g = wf + 4096;
    int n16 = m;
    float b1v[8], b2v[4];
    #pragma unroll
    for (int nt = 0; nt < 8; ++nt) b1v[nt] = b1[nt*16 + n16];
    #pragma unroll
    for (int n2 = 0; n2 < 4; ++n2) b2v[n2] = b2[n2*16 + n16];

    uint4 a0 = *(uint4*)(se + (wv*2+0)*256 + lane*4);
    uint4 a1 = *(uint4*)(se + (wv*2+1)*256 + lane*4);
    f32x4 D1[8];
    #pragma unroll
    for (int nt = 0; nt < 8; ++nt) D1[nt] = (f32x4){0.f,0.f,0.f,0.f};
    #pragma unroll
    for (int nt = 0; nt < 8; ++nt) {
        uint4 bk0 = *(const uint4*)(wf1g + (nt*2+0)*256 + lane*4);
        uint4 bk1 = *(const uint4*)(wf1g + (nt*2+1)*256 + lane*4);
        D1[nt] = __builtin_amdgcn_mfma_f32_16x16x32_bf16(u4s8(a0), u4s8(bk0), D1[nt], 0, 0, 0);
        D1[nt] = __builtin_amdgcn_mfma_f32_16x16x32_bf16(u4s8(a1), u4s8(bk1), D1[nt], 0, 0, 0);
    }
    f32x4 D2[4];
    #pragma unroll
    for (int n2 = 0; n2 < 4; ++n2) D2[n2] = (f32x4){0.f,0.f,0.f,0.f};
    unsigned* shwv = sh + wv*256;
    unsigned short* shw = (unsigned short*)shwv;
    for (int kc2 = 0; kc2 < 4; ++kc2) {
        #pragma unroll
        for (int h2 = 0; h2 < 2; ++h2) {
            int nt = kc2*2 + h2;
            #pragma unroll
            for (int r = 0; r < 4; ++r) {
                float hval = fmaxf(D1[nt][r] + b1v[nt], 0.f);
                int mrow = q*4 + r;
                int k = h2*16 + n16;
                shw[((k >> 3)*16 + mrow)*8 + (k & 7)] = f2bf(hval);
            }
        }
        uint4 ah = *(uint4*)(shwv + lane*4);        // same-wave LDS RAW: in-order
        #pragma unroll
        for (int n2 = 0; n2 < 4; ++n2) {
            uint4 bb = *(const uint4*)(wf2g + (kc2*4 + n2)*256 + lane*4);
            D2[n2] = __builtin_amdgcn_mfma_f32_16x16x32_bf16(u4s8(ah), u4s8(bb), D2[n2], 0, 0, 0);
        }
    }
    // residual + b2 into regs
    float vals[4][4];
    unsigned short* seu = (unsigned short*)se;
    #pragma unroll
    for (int n2 = 0; n2 < 4; ++n2) {
        int c = n2*16 + n16;
        int kc = c >> 5, qq = (c & 31) >> 3, jj = c & 7;
        #pragma unroll
        for (int r = 0; r < 4; ++r) {
            int pxt = q*4 + r;
            float resid = bf2f(seu[((wv*2+kc)*64 + qq*16 + pxt)*8 + jj]);
            vals[n2][r] = D2[n2][r] + resid + b2v[n2];
        }
    }
    __syncthreads();                                 // se dead; reuse as staging

    // ---- coalesced epilogue: 2 rounds of 32 channels via fp32 staging ----
    float* stg = (float*)lds;                        // [32 rows][stride 132]
    float* outb = out + (size_t)b*CC*HWSZ;
    #pragma unroll
    for (int g = 0; g < 2; ++g) {
        #pragma unroll
        for (int hn2 = 0; hn2 < 2; ++hn2) {
            int n2 = 2*g + hn2;
            int row = (n2 & 1)*16 + n16;
            float4 v4 = make_float4(vals[n2][0], vals[n2][1], vals[n2][2], vals[n2][3]);
            *(float4*)&stg[row*132 + wv*16 + q*4] = v4;
        }
        __syncthreads();
        #pragma unroll
        for (int rr = 0; rr < 2; ++rr) {
            int r0 = (wv*2 + rr)*2 + (lane >> 5);    // 0..31
            int px4 = (lane & 31) * 4;
            float4 v = *(float4*)&stg[r0*132 + px4];
            *(float4*)&outb[(size_t)(g*32 + r0)*HWSZ + pb + px4] = v;
        }
        if (g == 0) __syncthreads();
    }
}

extern "C" void kernel_launch(void* const* d_in, const int* in_sizes, int n_in,
                              void* d_out, int out_size, void* d_ws, size_t ws_size,
                              hipStream_t stream) {
    const float* x  = (const float*)d_in[0];
    const float* gw = (const float*)d_in[1];
    const float* gb = (const float*)d_in[2];
    const float* w1 = (const float*)d_in[3];
    const float* b1 = (const float*)d_in[4];
    const float* w2 = (const float*)d_in[5];
    const float* b2 = (const float*)d_in[6];
    float* out = (float*)d_out;

    // ws layout (floats): df | nrm | gnacc(256) | mmmax(4) | mmmin(4) | wf(8192u) | xt
    float* df       = (float*)d_ws;
    float* nrm      = df + 147456;
    float* gnacc    = nrm + 147456;
    unsigned* mmmax = (unsigned*)(gnacc + 256);
    unsigned* mmmin = mmmax + 4;
    unsigned* wf    = mmmin + 4;
    float* xtp      = (float*)(wf + 8192);           // 2359296 floats (9.4 MB)

    const size_t NEED = (size_t)(147456*2 + 256 + 8 + 8192 + (size_t)BB*CC*HWSZ) * 4;
    bool big = ws_size >= NEED;

    // init: gnacc+mmmax zero (contiguous), mmmin = 0xFFFFFFFF (uint-min identity)
    hipMemsetAsync(gnacc, 0, (256 + 4) * sizeof(float), stream);
    hipMemsetAsync(mmmin, 0xFF, 4 * sizeof(unsigned), stream);

    if (big) {
        k_pre<1>  <<<BB*BPB, 256, 0, stream>>>(x, w1, w2, wf, df, nrm, gnacc,
                                               mmmin, mmmax, xtp);
        k_fused<1><<<BB*FBPB, FTH, 0, stream>>>(x, xtp, df, nrm, mmmin, mmmax,
                                                gnacc, gw, gb, wf, b1, b2, out);
    } else {
        k_pre<0>  <<<BB*BPB, 256, 0, stream>>>(x, w1, w2, wf, df, nrm, gnacc,
                                               mmmin, mmmax, nullptr);
        k_fused<0><<<BB*FBPB, FTH, 0, stream>>>(x, nullptr, df, nrm, mmmin, mmmax,
                                                gnacc, gw, gb, wf, b1, b2, out);
    }
}

// Round 8
// 183.018 us; speedup vs baseline: 1.1868x; 1.1868x over previous
//
#include <hip/hip_runtime.h>
#include <hip/hip_bf16.h>

#define BB 4
#define CC 64
#define HH 192
#define WW 192
#define HWSZ (HH*WW)          // 36864
#define HD 96
#define WD 96
#define GG 32
// fused kernel geometry: 512 threads, 128 pixels (4 threads/pixel in phase 1)
#define FTH 512
#define FPX 128
#define FBPB (HWSZ/FPX)       // 288 blocks per batch; grid 1152
// pre kernel geometry: 256 threads, 128 pixels (4px x 8ch per thread)
#define PBLK 128
#define BPB (HWSZ/PBLK)       // 288 blocks per batch; grid 1152

typedef short short8 __attribute__((ext_vector_type(8)));
typedef float f32x4  __attribute__((ext_vector_type(4)));

__device__ __forceinline__ unsigned short f2bf(float f) {
    unsigned u = __float_as_uint(f);
    return (unsigned short)((u + 0x7FFFu + ((u >> 16) & 1u)) >> 16);
}
__device__ __forceinline__ float bf2f(unsigned short s) {
    return __uint_as_float(((unsigned)s) << 16);
}
__device__ __forceinline__ unsigned pk2(float a, float b) {
    return (unsigned)f2bf(a) | ((unsigned)f2bf(b) << 16);
}
__device__ __forceinline__ short8 u4s8(uint4 u) {
    union { uint4 a; short8 b; } cvt; cvt.a = u; return cvt.b;
}

// XCD-slab swizzle for 1152-block grids: presumed xcd = bid%8; give each XCD a
// contiguous 144-block slab so its 4MB L2 holds that slab's x rows.
__device__ __forceinline__ int swz1152(int bid) {
    return (bid & 7) * 144 + (bid >> 3);
}

// ---- single-pass pre-kernel: on-the-fly down+up, df, ||x||, GN sums, min/max ----
// Round-1 configuration: plain __launch_bounds__(256). Do not cap occupancy
// (round-4 (256,4): -20us; round-5 (256,8): 200MB scratch spills).
// XT=1 additionally emits x_t[B][HW][C] (transposed copy) from the already-loaded
// center values via a 4-channel register buffer — feeds k_fused's coalesced path.
// Blocks 0..15 also pack w1/w2 into MFMA B-frag order (cold branch).
template<int XT>
__global__ __launch_bounds__(256) void k_pre(const float* __restrict__ x,
                                             const float* __restrict__ w1,
                                             const float* __restrict__ w2,
                                             unsigned* __restrict__ wf,
                                             float* __restrict__ df,
                                             float* __restrict__ nrm,
                                             float* __restrict__ gnacc,
                                             unsigned* __restrict__ mmmin,
                                             unsigned* __restrict__ mmmax,
                                             float* __restrict__ xt) {
    __shared__ float sgn[64];
    __shared__ float wmn[4], wmx[4];
    int tid = threadIdx.x;
    if (tid < 64) sgn[tid] = 0.f;
    __syncthreads();

    // ---- weight prep (blocks 0..15 only), 2 items/thread, covers 8192 ----
    if (blockIdx.x < 16) {
        #pragma unroll
        for (int rep = 0; rep < 2; ++rep) {
            int i = blockIdx.x*512 + rep*256 + tid;
            if (i < 4096) {
                float2 v = ((const float2*)w1)[i];    // j = i>>5, c0 = (i&31)*2
                int j = i >> 5, cp = i & 31, c0 = cp << 1;
                int fi = ((j >> 4) << 1) + (c0 >> 5);
                int ln = (((c0 & 31) >> 3) << 4) + (j & 15);
                wf[fi*256 + ln*4 + (cp & 3)] = pk2(v.x, v.y);
            } else {
                int i2 = i - 4096;
                float2 v = ((const float2*)w2)[i2];   // c = i2>>6, j0 = (i2&63)*2
                int c = i2 >> 6, jp = i2 & 63, j0 = jp << 1;
                int fi = ((j0 >> 5) << 2) + (c >> 4);
                int ln = (((j0 & 31) >> 3) << 4) + (c & 15);
                wf[4096 + fi*256 + ln*4 + (jp & 3)] = pk2(v.x, v.y);
            }
        }
    }

    int virt = swz1152(blockIdx.x);
    int b = virt / BPB;
    int pb = (virt % BPB) * PBLK;
    int wave = tid >> 6, lane = tid & 63;
    int oct = lane >> 3, grp = lane & 7;
    int p0 = pb + wave*32 + grp*4;
    int h = p0 / WW, w0 = p0 % WW;

    // vertical source mapping (same formula/association as reference)
    float hs = fminf(fmaxf(0.5f*(float)h - 0.25f, 0.f), 95.f);
    int hl = (int)hs; int hh2 = min(hl+1, 95); float fh = hs - (float)hl;
    int r0 = 2*hl, r1 = 2*hh2;

    // horizontal: 4 px share a 4-wide xd column window starting at t0
    int t0 = min(max(w0/2 - 1, 0), 92);
    float wc[4][4];
    #pragma unroll
    for (int i = 0; i < 4; ++i) {
        float wsr = fminf(fmaxf(0.5f*(float)(w0+i) - 0.25f, 0.f), 95.f);
        int wl = (int)wsr; int wh = min(wl+1, 95); float fw = wsr - (float)wl;
        int kl = wl - t0, kh = wh - t0;
        #pragma unroll
        for (int k = 0; k < 4; ++k)
            wc[i][k] = ((k==kl) ? (1.f-fw) : 0.f) + ((k==kh) ? fw : 0.f);
    }

    const float* xb = x + (size_t)b*CC*HWSZ;
    float d[4]  = {0.f,0.f,0.f,0.f};
    float qn[4] = {0.f,0.f,0.f,0.f};
    float gs[4] = {0.f,0.f,0.f,0.f};
    float gq[4] = {0.f,0.f,0.f,0.f};
    #pragma unroll
    for (int half = 0; half < 2; ++half) {
        float4 xbuf[4];
        #pragma unroll
        for (int k4 = 0; k4 < 4; ++k4) {
            int cc = half*4 + k4;
            const float* pc = xb + (size_t)(oct*8 + cc)*HWSZ;
            float4 xc = *(const float4*)(pc + h*WW + w0);
            xbuf[k4] = xc;
            const float* pa = pc + r0*WW + 2*t0;
            const float* pq = pc + r1*WW + 2*t0;
            float T[4];
            #pragma unroll
            for (int k = 0; k < 4; ++k) {
                float2 a0 = *(const float2*)(pa + 2*k);
                float2 a1 = *(const float2*)(pa + WW + 2*k);
                float2 c0 = *(const float2*)(pq + 2*k);
                float2 c1 = *(const float2*)(pq + WW + 2*k);
                // 2x2 average, vertical pairs first (matches reference association)
                float xdA = 0.25f*((a0.x + a1.x) + (a0.y + a1.y));
                float xdB = 0.25f*((c0.x + c1.x) + (c0.y + c1.y));
                T[k] = (1.f-fh)*xdA + fh*xdB;        // h-lerp per column
            }
            float xv[4] = {xc.x, xc.y, xc.z, xc.w};
            float sch = 0.f, qch = 0.f;
            #pragma unroll
            for (int i = 0; i < 4; ++i) {
                // w-lerp via sparse dot: exactly (1-fw)*t0 + fw*t1 (zero terms exact)
                float du = (wc[i][0]*T[0] + wc[i][1]*T[1]) + (wc[i][2]*T[2] + wc[i][3]*T[3]);
                d[i] += fabsf(xv[i] - du);
                float x2 = xv[i]*xv[i];
                qn[i] += x2;
                sch += xv[i];
                qch += x2;
            }
            gs[cc>>1] += sch;
            gq[cc>>1] += qch;
        }
        if (XT) {
            // transpose 4ch x 4px register tile -> x_t[p][c] (16B contiguous stores)
            #pragma unroll
            for (int i = 0; i < 4; ++i) {
                float4 v4 = make_float4(((const float*)&xbuf[0])[i],
                                        ((const float*)&xbuf[1])[i],
                                        ((const float*)&xbuf[2])[i],
                                        ((const float*)&xbuf[3])[i]);
                *(float4*)(xt + ((size_t)b*HWSZ + p0 + i)*CC + oct*8 + half*4) = v4;
            }
        }
    }
    // reduce df / ||x||^2 over the 8 channel-octets (butterfly: all lanes get sum)
    #pragma unroll
    for (int o = 8; o <= 32; o <<= 1) {
        #pragma unroll
        for (int i = 0; i < 4; ++i) {
            d[i]  += __shfl_xor(d[i], o);
            qn[i] += __shfl_xor(qn[i], o);
        }
    }
    if (oct == 0) {
        *(float4*)(df  + (size_t)b*HWSZ + p0) = make_float4(d[0], d[1], d[2], d[3]);
        *(float4*)(nrm + (size_t)b*HWSZ + p0) =
            make_float4(sqrtf(qn[0]), sqrtf(qn[1]), sqrtf(qn[2]), sqrtf(qn[3]));
    }
    // block min/max of df (duplicates across octs are harmless for min/max)
    float mn = fminf(fminf(d[0], d[1]), fminf(d[2], d[3]));
    float mx = fmaxf(fmaxf(d[0], d[1]), fmaxf(d[2], d[3]));
    #pragma unroll
    for (int o = 1; o < 64; o <<= 1) {
        mn = fminf(mn, __shfl_xor(mn, o));
        mx = fmaxf(mx, __shfl_xor(mx, o));
    }
    if (lane == 0) { wmn[wave] = mn; wmx[wave] = mx; }
    // GN group sums: reduce over the 8 px-groups (xor 1,2,4 within octet)
    #pragma unroll
    for (int o = 1; o <= 4; o <<= 1) {
        #pragma unroll
        for (int j = 0; j < 4; ++j) {
            gs[j] += __shfl_xor(gs[j], o);
            gq[j] += __shfl_xor(gq[j], o);
        }
    }
    if (grp == 0) {
        #pragma unroll
        for (int j = 0; j < 4; ++j) {
            atomicAdd(&sgn[2*(oct*4+j)],   gs[j]);
            atomicAdd(&sgn[2*(oct*4+j)+1], gq[j]);
        }
    }
    __syncthreads();
    if (tid < 64) atomicAdd(&gnacc[(size_t)b*64 + tid], sgn[tid]);
    if (tid == 0) {
        float bmn = fminf(fminf(wmn[0], wmn[1]), fminf(wmn[2], wmn[3]));
        float bmx = fmaxf(fmaxf(wmx[0], wmx[1]), fmaxf(wmx[2], wmx[3]));
        atomicMin(&mmmin[b], __float_as_uint(bmn));
        atomicMax(&mmmax[b], __float_as_uint(bmx));
    }
}

// ------- fused: sims + top-k softmax + GN affine (phase 1) + MFMA FFN (phase 2) -------
// XT=1: phase-1 reads x_t[B][HW][C], j-major: only ONE neighbor quad (4 float4)
// live at a time; all local arrays compile-time-indexed (rule #20 — round 7's
// float4 N[9] + address-of pattern spilled 141MB to scratch). FP order identical
// to the scalar path.
// XT=0: round-6 measured path (63.0us). (512,4), LDS 24576 B.
template<int XT>
__global__ __launch_bounds__(FTH, 4) void k_fused(const float* __restrict__ x,
                                                  const float* __restrict__ xt,
                                                  const float* __restrict__ df,
                                                  const float* __restrict__ nrm,
                                                  const unsigned* __restrict__ mmmin,
                                                  const unsigned* __restrict__ mmmax,
                                                  const float* __restrict__ gnacc,
                                                  const float* __restrict__ gw,
                                                  const float* __restrict__ gb,
                                                  const unsigned* __restrict__ wf,
                                                  const float* __restrict__ b1,
                                                  const float* __restrict__ b2,
                                                  float* __restrict__ out) {
    __shared__ __align__(16) unsigned char lds[24576];
    unsigned* se = (unsigned*)lds;                  // 4096 uints
    unsigned* sh = (unsigned*)(lds + 16384);        // 2048 uints
    float* gnv = (float*)(lds + 16384);             // [32 groups][mu, rsigma]

    int tid = threadIdx.x;
    int wv = tid >> 6, lane = tid & 63;
    int q = lane >> 4, m = lane & 15;               // quarter (ch group), pixel row

    int virt = swz1152(blockIdx.x);
    int b = virt / FBPB;
    int pb = (virt % FBPB) * FPX;
    int pxl = wv*16 + m;                            // 0..127 local pixel
    int p = pb + pxl;
    int h = p / WW, w = p % WW;
    int cbase = q*16;

    // finalize GN stats in-block
    if (tid < 32) {
        float n = 2.f*HWSZ;
        float mu  = gnacc[(size_t)b*64 + 2*tid] / n;
        float var = gnacc[(size_t)b*64 + 2*tid + 1] / n - mu*mu;
        gnv[2*tid]   = mu;
        gnv[2*tid+1] = rsqrtf(var + 1e-5f);
    }
    __syncthreads();

    // ================= phase 1 =================
    float dmin = __uint_as_float(mmmin[b]);
    float dmax = __uint_as_float(mmmax[b]);
    float dfp = (df[b*HWSZ+p] - dmin) / (dmax - dmin + 1e-8f);
    dfp = dfp * dfp;
    bool maskv = dfp > 0.3f;
    float conn = 1.f + (maskv ? fmaxf(rintf(dfp * 15.f), 0.f) : 0.f);
    bool process = conn > 1.f;
    int kk = (int)fminf(conn, 9.f);

    const float* xb = x + (size_t)b*CC*HWSZ + p;                 // XT=0 path
    const float* pt = xt + ((size_t)b*HWSZ + p)*CC + cbase;      // XT=1 path
    const int dhv[9] = {-1,-1,-1, 0,0,0, 1,1,1};
    const int dwv[9] = {-1, 0, 1,-1,0,1,-1,0,1};
    bool valid[9]; int offc[9];
    #pragma unroll
    for (int j = 0; j < 9; ++j) {
        int hn = h + dhv[j], wn = w + dwv[j];
        valid[j] = (hn >= 0) && (hn < HH) && (wn >= 0) && (wn < WW);
        offc[j] = valid[j] ? (dhv[j]*WW + dwv[j]) : 0;
    }
    float wtc[9];
    #pragma unroll
    for (int j = 0; j < 9; ++j) wtc[j] = 0.f;

    // center channel run (XT=1): 16 floats, compile-time-indexed register array
    float xa[16];
    if (XT) {
        float4 X0 = *(const float4*)(pt + 0);
        float4 X1 = *(const float4*)(pt + 4);
        float4 X2 = *(const float4*)(pt + 8);
        float4 X3 = *(const float4*)(pt + 12);
        xa[0]=X0.x;  xa[1]=X0.y;  xa[2]=X0.z;  xa[3]=X0.w;
        xa[4]=X1.x;  xa[5]=X1.y;  xa[6]=X1.z;  xa[7]=X1.w;
        xa[8]=X2.x;  xa[9]=X2.y;  xa[10]=X2.z; xa[11]=X2.w;
        xa[12]=X3.x; xa[13]=X3.y; xa[14]=X3.z; xa[15]=X3.w;
    }

    if (process) {
        float dot[9];
        if (XT) {
            #pragma unroll
            for (int j = 0; j < 9; ++j) {           // j-major: 4 float4 live max
                const float* nb = pt + (ptrdiff_t)offc[j]*CC;
                float4 n0 = *(const float4*)(nb + 0);
                float4 n1 = *(const float4*)(nb + 4);
                float4 n2 = *(const float4*)(nb + 8);
                float4 n3 = *(const float4*)(nb + 12);
                float na[16];
                na[0]=n0.x;  na[1]=n0.y;  na[2]=n0.z;  na[3]=n0.w;
                na[4]=n1.x;  na[5]=n1.y;  na[6]=n1.z;  na[7]=n1.w;
                na[8]=n2.x;  na[9]=n2.y;  na[10]=n2.z; na[11]=n2.w;
                na[12]=n3.x; na[13]=n3.y; na[14]=n3.z; na[15]=n3.w;
                float s = 0.f;
                #pragma unroll
                for (int cc = 0; cc < 16; ++cc)     // cc ascending == scalar order
                    s += xa[cc] * na[cc];
                dot[j] = s;
            }
        } else {
            #pragma unroll
            for (int j = 0; j < 9; ++j) dot[j] = 0.f;
            #pragma unroll 4
            for (int cc = 0; cc < 16; ++cc) {
                const float* pc = xb + (size_t)(cbase + cc)*HWSZ;
                float xc = pc[0];
                #pragma unroll
                for (int j = 0; j < 9; ++j)
                    dot[j] += xc * pc[offc[j]];
            }
        }
        #pragma unroll
        for (int j = 0; j < 9; ++j) {
            dot[j] += __shfl_xor(dot[j], 16);       // 4 quarters share px
            dot[j] += __shfl_xor(dot[j], 32);
        }
        float nc = fmaxf(nrm[b*HWSZ+p], 1e-12f);
        float sim[9];
        #pragma unroll
        for (int j = 0; j < 9; ++j) {
            float nj = fmaxf(nrm[b*HWSZ+p+offc[j]], 1e-12f);
            sim[j] = valid[j] ? dot[j] / (nc * nj) : 0.f;
        }
        float S = 0.f;
        float wt[9];
        #pragma unroll
        for (int j = 0; j < 9; ++j) {
            int rank = 0;
            #pragma unroll
            for (int l = 0; l < 9; ++l)
                rank += (sim[l] > sim[j]) || (sim[l] == sim[j] && l < j);
            float ex = (rank < kk) ? expf(sim[j]) : 0.f;  // stable argsort(-sim) top-k
            wt[j] = ex; S += ex;
        }
        float inv = 1.f / fmaxf(S, 1e-12f);
        #pragma unroll
        for (int j = 0; j < 9; ++j)
            wtc[j] = valid[j] ? wt[j] * inv : 0.f;
    }

    float e[16];
    if (XT) {
        float acc[16];
        if (process) {
            #pragma unroll
            for (int cc = 0; cc < 16; ++cc) acc[cc] = 0.f;
            #pragma unroll
            for (int j = 0; j < 9; ++j) {           // j ascending == scalar order
                const float* nb = pt + (ptrdiff_t)offc[j]*CC;
                float4 n0 = *(const float4*)(nb + 0);
                float4 n1 = *(const float4*)(nb + 4);
                float4 n2 = *(const float4*)(nb + 8);
                float4 n3 = *(const float4*)(nb + 12);
                float wj = wtc[j];
                acc[0]  += wj*n0.x;  acc[1]  += wj*n0.y;
                acc[2]  += wj*n0.z;  acc[3]  += wj*n0.w;
                acc[4]  += wj*n1.x;  acc[5]  += wj*n1.y;
                acc[6]  += wj*n1.z;  acc[7]  += wj*n1.w;
                acc[8]  += wj*n2.x;  acc[9]  += wj*n2.y;
                acc[10] += wj*n2.z;  acc[11] += wj*n2.w;
                acc[12] += wj*n3.x;  acc[13] += wj*n3.y;
                acc[14] += wj*n3.z;  acc[15] += wj*n3.w;
            }
        }
        #pragma unroll
        for (int cc = 0; cc < 16; ++cc) {
            int c = cbase + cc;
            float xc = xa[cc];
            float oc = process ? acc[cc] : xc;
            int g = c >> 1;
            float mu = gnv[2*g], is = gnv[2*g+1];
            e[cc] = oc + (xc - mu) * is * gw[c] + gb[c];
        }
    } else {
        #pragma unroll 4
        for (int cc = 0; cc < 16; ++cc) {
            int c = cbase + cc;
            const float* pc = xb + (size_t)c*HWSZ;
            float xc = pc[0];
            float oc;
            if (process) {
                float a = 0.f;
                #pragma unroll
                for (int j = 0; j < 9; ++j)
                    a += wtc[j] * pc[offc[j]];
                oc = a;
            } else oc = xc;
            int g = c >> 1;
            float mu = gnv[2*g], is = gnv[2*g+1];
            e[cc] = oc + (xc - mu) * is * gw[c] + gb[c];
        }
    }

    // e -> A-frag order: tile wv, kc=q>>1, k = 16*(q&1)+j
    {
        int kc = q >> 1, qo = q & 1;
        unsigned* dst = se + (wv*2 + kc)*256;
        int la = 32*qo + m;
        uint4 ua, ub;
        ua.x = pk2(e[0],e[1]);  ua.y = pk2(e[2],e[3]);
        ua.z = pk2(e[4],e[5]);  ua.w = pk2(e[6],e[7]);
        ub.x = pk2(e[8],e[9]);  ub.y = pk2(e[10],e[11]);
        ub.z = pk2(e[12],e[13]); ub.w = pk2(e[14],e[15]);
        *(uint4*)(dst + la*4)      = ua;
        *(uint4*)(dst + (la+16)*4) = ub;
    }
    __syncthreads();

    // ================= phase 2: MFMA FFN (tile = wv, 16 px) =================
    const unsigned* wf1g = wf;
    const unsigned* wf2g = wf + 4096;
    int n16 = m;
    float b1v[8], b2v[4];
    #pragma unroll
    for (int nt = 0; nt < 8; ++nt) b1v[nt] = b1[nt*16 + n16];
    #pragma unroll
    for (int n2 = 0; n2 < 4; ++n2) b2v[n2] = b2[n2*16 + n16];

    uint4 a0 = *(uint4*)(se + (wv*2+0)*256 + lane*4);
    uint4 a1 = *(uint4*)(se + (wv*2+1)*256 + lane*4);
    f32x4 D1[8];
    #pragma unroll
    for (int nt = 0; nt < 8; ++nt) D1[nt] = (f32x4){0.f,0.f,0.f,0.f};
    #pragma unroll
    for (int nt = 0; nt < 8; ++nt) {
        uint4 bk0 = *(const uint4*)(wf1g + (nt*2+0)*256 + lane*4);
        uint4 bk1 = *(const uint4*)(wf1g + (nt*2+1)*256 + lane*4);
        D1[nt] = __builtin_amdgcn_mfma_f32_16x16x32_bf16(u4s8(a0), u4s8(bk0), D1[nt], 0, 0, 0);
        D1[nt] = __builtin_amdgcn_mfma_f32_16x16x32_bf16(u4s8(a1), u4s8(bk1), D1[nt], 0, 0, 0);
    }
    f32x4 D2[4];
    #pragma unroll
    for (int n2 = 0; n2 < 4; ++n2) D2[n2] = (f32x4){0.f,0.f,0.f,0.f};
    unsigned* shwv = sh + wv*256;
    unsigned short* shw = (unsigned short*)shwv;
    for (int kc2 = 0; kc2 < 4; ++kc2) {
        #pragma unroll
        for (int h2 = 0; h2 < 2; ++h2) {
            int nt = kc2*2 + h2;
            #pragma unroll
            for (int r = 0; r < 4; ++r) {
                float hval = fmaxf(D1[nt][r] + b1v[nt], 0.f);
                int mrow = q*4 + r;
                int k = h2*16 + n16;
                shw[((k >> 3)*16 + mrow)*8 + (k & 7)] = f2bf(hval);
            }
        }
        uint4 ah = *(uint4*)(shwv + lane*4);        // same-wave LDS RAW: in-order
        #pragma unroll
        for (int n2 = 0; n2 < 4; ++n2) {
            uint4 bb = *(const uint4*)(wf2g + (kc2*4 + n2)*256 + lane*4);
            D2[n2] = __builtin_amdgcn_mfma_f32_16x16x32_bf16(u4s8(ah), u4s8(bb), D2[n2], 0, 0, 0);
        }
    }
    // residual + b2 into regs
    float vals[4][4];
    unsigned short* seu = (unsigned short*)se;
    #pragma unroll
    for (int n2 = 0; n2 < 4; ++n2) {
        int c = n2*16 + n16;
        int kc = c >> 5, qq = (c & 31) >> 3, jj = c & 7;
        #pragma unroll
        for (int r = 0; r < 4; ++r) {
            int pxt = q*4 + r;
            float resid = bf2f(seu[((wv*2+kc)*64 + qq*16 + pxt)*8 + jj]);
            vals[n2][r] = D2[n2][r] + resid + b2v[n2];
        }
    }
    __syncthreads();                                 // se dead; reuse as staging

    // ---- coalesced epilogue: 2 rounds of 32 channels via fp32 staging ----
    float* stg = (float*)lds;                        // [32 rows][stride 132]
    float* outb = out + (size_t)b*CC*HWSZ;
    #pragma unroll
    for (int g = 0; g < 2; ++g) {
        #pragma unroll
        for (int hn2 = 0; hn2 < 2; ++hn2) {
            int n2 = 2*g + hn2;
            int row = (n2 & 1)*16 + n16;
            float4 v4 = make_float4(vals[n2][0], vals[n2][1], vals[n2][2], vals[n2][3]);
            *(float4*)&stg[row*132 + wv*16 + q*4] = v4;
        }
        __syncthreads();
        #pragma unroll
        for (int rr = 0; rr < 2; ++rr) {
            int r0 = (wv*2 + rr)*2 + (lane >> 5);    // 0..31
            int px4 = (lane & 31) * 4;
            float4 v = *(float4*)&stg[r0*132 + px4];
            *(float4*)&outb[(size_t)(g*32 + r0)*HWSZ + pb + px4] = v;
        }
        if (g == 0) __syncthreads();
    }
}

extern "C" void kernel_launch(void* const* d_in, const int* in_sizes, int n_in,
                              void* d_out, int out_size, void* d_ws, size_t ws_size,
                              hipStream_t stream) {
    const float* x  = (const float*)d_in[0];
    const float* gw = (const float*)d_in[1];
    const float* gb = (const float*)d_in[2];
    const float* w1 = (const float*)d_in[3];
    const float* b1 = (const float*)d_in[4];
    const float* w2 = (const float*)d_in[5];
    const float* b2 = (const float*)d_in[6];
    float* out = (float*)d_out;

    // ws layout (floats): df | nrm | gnacc(256) | mmmax(4) | mmmin(4) | wf(8192u) | xt
    float* df       = (float*)d_ws;
    float* nrm      = df + 147456;
    float* gnacc    = nrm + 147456;
    unsigned* mmmax = (unsigned*)(gnacc + 256);
    unsigned* mmmin = mmmax + 4;
    unsigned* wf    = mmmin + 4;
    float* xtp      = (float*)(wf + 8192);           // 2359296 floats (9.4 MB/batch x4)

    const size_t NEED = (size_t)(147456*2 + 256 + 8 + 8192 + (size_t)BB*CC*HWSZ) * 4;
    bool big = ws_size >= NEED;

    // init: gnacc+mmmax zero (contiguous), mmmin = 0xFFFFFFFF (uint-min identity)
    hipMemsetAsync(gnacc, 0, (256 + 4) * sizeof(float), stream);
    hipMemsetAsync(mmmin, 0xFF, 4 * sizeof(unsigned), stream);

    if (big) {
        k_pre<1>  <<<BB*BPB, 256, 0, stream>>>(x, w1, w2, wf, df, nrm, gnacc,
                                               mmmin, mmmax, xtp);
        k_fused<1><<<BB*FBPB, FTH, 0, stream>>>(x, xtp, df, nrm, mmmin, mmmax,
                                                gnacc, gw, gb, wf, b1, b2, out);
    } else {
        k_pre<0>  <<<BB*BPB, 256, 0, stream>>>(x, w1, w2, wf, df, nrm, gnacc,
                                               mmmin, mmmax, nullptr);
        k_fused<0><<<BB*FBPB, FTH, 0, stream>>>(x, nullptr, df, nrm, mmmin, mmmax,
                                                gnacc, gw, gb, wf, b1, b2, out);
    }
}